// Round 11
// baseline (224.900 us; speedup 1.0000x reference)
//
#include <hip/hip_runtime.h>

typedef __bf16 bf16_t;
typedef __bf16 bf16x8 __attribute__((ext_vector_type(8)));
typedef __bf16 bf16x4 __attribute__((ext_vector_type(4)));
typedef float f32x4 __attribute__((ext_vector_type(4)));

#define GLOAD_LDS16(gptr, lptr)                                                              \
  __builtin_amdgcn_global_load_lds((const __attribute__((address_space(1))) void*)(gptr),    \
                                   (__attribute__((address_space(3))) void*)(lptr), 16, 0, 0)

__device__ __forceinline__ f32x4 f32x4_zero() {
  f32x4 v; v[0] = 0.f; v[1] = 0.f; v[2] = 0.f; v[3] = 0.f; return v;
}

// ---------------------------------------------------------------- fused casts f32 -> bf16
__global__ void cast3_kernel(const float* __restrict__ a, const float* __restrict__ b,
                             const float* __restrict__ c, bf16_t* __restrict__ oa,
                             bf16_t* __restrict__ ob, bf16_t* __restrict__ oc) {
  int i = blockIdx.x * blockDim.x + threadIdx.x;
  const float* src; bf16_t* dst; int j;
  if (i < 2097152) { src = a; dst = oa; j = i; }
  else if (i < 2883584) { src = b; dst = ob; j = i - 2097152; }
  else { src = c; dst = oc; j = i - 2883584; }
  float4 v = ((const float4*)src)[j];
  bf16x4 o;
  o[0] = (bf16_t)v.x; o[1] = (bf16_t)v.y; o[2] = (bf16_t)v.z; o[3] = (bf16_t)v.w;
  ((bf16x4*)dst)[j] = o;
}

// ---------------------------------------------------------------- GEMM  C[M,N] = A[M,K] * B[N,K]^T
// (byte-identical to rounds 8/9: 256x128 tile, BK=64, 8 waves, 3-slot ring, counted vmcnt(6),
//  XOR-granule swizzle, setprio; MODE-1 epilogue fuses RoPE for q/k and transposed V write)
#define GT_AELE 16384  // 256*64 bf16 (32KB)
#define GT_BELE 8192   // 128*64 bf16 (16KB)
#define GT_TILE (GT_AELE + GT_BELE)

__device__ __forceinline__ void gt_stage(const bf16_t* __restrict__ A,
                                         const bf16_t* __restrict__ B, bf16_t* buf,
                                         int bm, int bn, int t, int K, int tid) {
#pragma unroll
  for (int i = 0; i < 4; i++) {  // A: 256 rows x 8 granules of 16B
    int gi = tid + i * 512;
    int row = gi >> 3, g = gi & 7;
    const bf16_t* src = A + (size_t)(bm * 256 + row) * K + t * 64 + ((g ^ (row & 7)) << 3);
    GLOAD_LDS16(src, buf + gi * 8);
  }
#pragma unroll
  for (int i = 0; i < 2; i++) {  // B: 128 rows x 8 granules
    int gi = tid + i * 512;
    int row = gi >> 3, g = gi & 7;
    const bf16_t* src = B + (size_t)(bn * 128 + row) * K + t * 64 + ((g ^ (row & 7)) << 3);
    GLOAD_LDS16(src, buf + GT_AELE + gi * 8);
  }
}

template <int MODE>
__global__ __launch_bounds__(512, 1) void gemm_bt_kernel(
    const bf16_t* __restrict__ A, const bf16_t* __restrict__ B, float* __restrict__ C,
    bf16_t* __restrict__ oq, bf16_t* __restrict__ ok_, bf16_t* __restrict__ ov,
    const float* __restrict__ cosp, const float* __restrict__ sinp,
    int M, int N, int K) {
  __shared__ bf16_t lds[3 * GT_TILE];  // 147456 B

  const int tid = threadIdx.x;
  const int lane = tid & 63;
  const int wid = tid >> 6;
  const int wr = wid >> 1;      // 0..3  (M quadrant, 64 rows)
  const int wc = wid & 1;       // 0..1  (N half, 64 cols)
  const int l16 = lane & 15;
  const int qd = lane >> 4;
  const int bm = blockIdx.x, bn = blockIdx.y;

  f32x4 acc[4][4];
#pragma unroll
  for (int m = 0; m < 4; m++)
#pragma unroll
    for (int n = 0; n < 4; n++) acc[m][n] = f32x4_zero();

  const int NT = K >> 6;  // 16

  gt_stage(A, B, lds, bm, bn, 0, K, tid);
  gt_stage(A, B, lds + GT_TILE, bm, bn, 1, K, tid);
  asm volatile("s_waitcnt vmcnt(6)" ::: "memory");
  __builtin_amdgcn_s_barrier();
  __builtin_amdgcn_sched_barrier(0);

  int s = 0;  // buffer holding tile j
  for (int j = 0; j < NT; ++j) {
    if (j + 2 < NT) {
      int s2 = s + 2; if (s2 >= 3) s2 -= 3;
      gt_stage(A, B, lds + s2 * GT_TILE, bm, bn, j + 2, K, tid);
    }

    const bf16_t* bufc = lds + s * GT_TILE;
    bf16x8 af[4][2], bf[4][2];
#pragma unroll
    for (int m = 0; m < 4; m++)
#pragma unroll
      for (int kk = 0; kk < 2; kk++) {
        int row = wr * 64 + m * 16 + l16;
        af[m][kk] = *(const bf16x8*)&bufc[row * 64 + (((kk * 4 + qd) ^ (row & 7)) << 3)];
      }
#pragma unroll
    for (int n = 0; n < 4; n++)
#pragma unroll
      for (int kk = 0; kk < 2; kk++) {
        int row = wc * 64 + n * 16 + l16;
        bf[n][kk] = *(const bf16x8*)&bufc[GT_AELE + row * 64 + (((kk * 4 + qd) ^ (row & 7)) << 3)];
      }

    __builtin_amdgcn_s_setprio(1);
#pragma unroll
    for (int m = 0; m < 4; m++)
#pragma unroll
      for (int n = 0; n < 4; n++)
#pragma unroll
        for (int kk = 0; kk < 2; kk++)
          acc[m][n] = __builtin_amdgcn_mfma_f32_16x16x32_bf16(af[m][kk], bf[n][kk], acc[m][n], 0, 0, 0);
    __builtin_amdgcn_s_setprio(0);

    if (j + 2 < NT) {
      asm volatile("s_waitcnt vmcnt(6)" ::: "memory");
    } else {
      asm volatile("s_waitcnt vmcnt(0)" ::: "memory");
    }
    __builtin_amdgcn_s_barrier();
    __builtin_amdgcn_sched_barrier(0);
    s = (s == 2) ? 0 : s + 1;
  }

  if (MODE == 0) {
#pragma unroll
    for (int m = 0; m < 4; m++)
#pragma unroll
      for (int n = 0; n < 4; n++)
#pragma unroll
        for (int r = 0; r < 4; r++) {
          int row = bm * 256 + wr * 64 + m * 16 + qd * 4 + r;
          int col = bn * 128 + wc * 64 + n * 16 + l16;
          C[(size_t)row * N + col] = acc[m][n][r];
        }
  } else {
    const int colbase = bn * 128 + wc * 64;     // 64-aligned -> single head per wave
    const int part = colbase >> 10;             // uniform per block (bn 0-7 q, 8-15 k, 16-23 v)
    const int h = (colbase & 1023) >> 6;
    if (part == 2) {
      // v: transpose via per-wave 8KB LDS region (ring is dead after the K-loop).
      bf16_t* lw = lds + wid * 4096;  // [64 d][8 granules of 8 bf16]
#pragma unroll
      for (int m = 0; m < 4; m++)
#pragma unroll
        for (int n = 0; n < 4; n++) {
          int d = n * 16 + l16;
          int gr = (m * 2 + (qd >> 1)) ^ (d & 7);   // t-chunk (t_local>>3), swizzled
          bf16x4 w;
          w[0] = (bf16_t)acc[m][n][0];
          w[1] = (bf16_t)acc[m][n][1];
          w[2] = (bf16_t)acc[m][n][2];
          w[3] = (bf16_t)acc[m][n][3];
          *(bf16x4*)&lw[d * 64 + gr * 8 + (qd & 1) * 4] = w;
        }
      asm volatile("s_waitcnt lgkmcnt(0)" ::: "memory");
      __builtin_amdgcn_sched_barrier(0);
      const int rowbase = bm * 256 + wr * 64;      // 64-aligned -> single batch per wave
      const int bb = rowbase >> 11, tb = rowbase & 2047;
      bf16_t* vbase = ov + ((size_t)(bb * 16 + h) * 64) * 2048 + tb;
#pragma unroll
      for (int it = 0; it < 8; it++) {
        int d = it * 8 + (lane >> 3);
        int g = lane & 7;
        *(bf16x8*)&vbase[(size_t)d * 2048 + g * 8] =
            *(const bf16x8*)&lw[d * 64 + ((g ^ (d & 7)) << 3)];
      }
    } else {
      // q (part 0, 0.125*log2e folded) or k (part 1): fused RoPE in fp32.
      bf16_t* dst = (part == 0) ? oq : ok_;
      const float qsc = (part == 0) ? 0.18033688011112042f : 1.0f;
#pragma unroll
      for (int m = 0; m < 4; m++)
#pragma unroll
        for (int r = 0; r < 4; r++) {
          int row = bm * 256 + wr * 64 + m * 16 + qd * 4 + r;
          int b = row >> 11, t = row & 2047;
          size_t basei = (((size_t)(b * 16 + h)) * 2048 + t) * 64;
#pragma unroll
          for (int nb = 0; nb < 2; nb++) {
            int d = nb * 16 + l16;
            float xl = acc[m][nb][r];
            float xh = acc[m][nb + 2][r];
            float cl = cosp[t * 64 + d], ch = cosp[t * 64 + d + 32];
            float sl = sinp[t * 64 + d], sh = sinp[t * 64 + d + 32];
            dst[basei + d]      = (bf16_t)((xl * cl - xh * sl) * qsc);
            dst[basei + d + 32] = (bf16_t)((xh * ch + xl * sh) * qsc);
          }
        }
    }
  }
}

// ---------------------------------------------------------------- banded flash attention
// Multi-q-tile blocks (4 q-tiles / 256 rows per block, union-window sweep, K/VT staged
// once per block per c). Q fragments in REGISTERS (direct global 16B loads, once per
// block) -> qs deleted, LDS 72KB -> 40KB. T14 register prefetch: next c's K/VT loads
// issue right after the current LDS write, hiding HBM/L2 latency under compute.
// NOTE: no forced min-waves launch bound (r10's __launch_bounds__(256,3) forced the
// allocator under the kernel's natural VGPR demand -> spill risk; removed).
// Fragment math identical to r9 (V arrives transposed; PV == QK^T structurally;
// wave-private ps -> lgkmcnt fence; fixed-max softmax; ones-MFMA row-sum).
__global__ __launch_bounds__(256) void attn_kernel(
    const bf16_t* __restrict__ qh, const bf16_t* __restrict__ kh,
    const bf16_t* __restrict__ vt, bf16_t* __restrict__ ao) {
  __shared__ bf16_t ks[2][64 * 64];   // 16KB: K double buffer
  __shared__ bf16_t vts[2][64 * 64];  // 16KB: VT double buffer
  __shared__ bf16_t ps[4][16 * 64];   // 8KB: per-wave P

  const int tid = threadIdx.x;
  const int lane = tid & 63;
  const int wid = tid >> 6;
  const int l16 = lane & 15;
  const int qd = lane >> 4;

  const int bh = blockIdx.x;          // 0..63
  const int chunk = blockIdx.y;       // 0..7 (256 q-rows each)
  const int b = bh >> 4, h = bh & 15;

  auto swz4 = [](int f) { int r = f >> 3; return r * 8 + ((f & 7) ^ (r & 7)); };

  // Q fragments straight from global: qfr[qt][kk] = Q[i0q + wid*16 + l16][(kk*4+qd)*8 ..]
  bf16x8 qfr[4][2];
#pragma unroll
  for (int qt = 0; qt < 4; qt++)
#pragma unroll
    for (int kk = 0; kk < 2; kk++)
      qfr[qt][kk] = *(const bf16x8*)(qh +
          ((size_t)bh * 2048 + chunk * 256 + qt * 64 + wid * 16 + l16) * 64 + (kk * 4 + qd) * 8);

  bf16x8 bones;
#pragma unroll
  for (int e = 0; e < 8; e++) bones[e] = (bf16_t)1.0f;

  f32x4 oacc[4][4];          // [qt][nb]
  float l_i[4][4];           // [qt][r]
#pragma unroll
  for (int qt = 0; qt < 4; qt++)
#pragma unroll
    for (int nb = 0; nb < 4; nb++) {
      oacc[qt][nb] = f32x4_zero();
      l_i[qt][nb] = 0.f;
    }

  const int cbase = chunk * 4;
  const int c0 = (cbase >= 4) ? cbase - 4 : 0;
  const int c1 = cbase + 3;

  // prefetch first K/VT tile into registers
  uint4 kr0, kr1, vr0, vr1;
  {
    const uint4* ksrc = (const uint4*)(kh + ((size_t)bh * 2048 + c0 * 64) * 64);
    kr0 = ksrc[tid]; kr1 = ksrc[tid + 256];
    vr0 = *(const uint4*)(vt + (size_t)(bh * 64 + (tid >> 3)) * 2048 + c0 * 64 + (tid & 7) * 8);
    int f2 = tid + 256;
    vr1 = *(const uint4*)(vt + (size_t)(bh * 64 + (f2 >> 3)) * 2048 + c0 * 64 + (f2 & 7) * 8);
  }

  for (int c = c0; c <= c1; c++) {
    const int p = c & 1;
    __syncthreads();  // reads of buf[p] (iteration c-2) complete before overwrite
    {  // write prefetched K[c], VT[c] (swz4 content)
      uint4* kdst = (uint4*)ks[p];
      uint4* vdst = (uint4*)vts[p];
      kdst[swz4(tid)] = kr0;
      kdst[swz4(tid + 256)] = kr1;
      vdst[swz4(tid)] = vr0;
      vdst[swz4(tid + 256)] = vr1;
    }
    if (c < c1) {  // T14: issue next tile's loads; latency hides under compute below
      const uint4* ksrc = (const uint4*)(kh + ((size_t)bh * 2048 + (c + 1) * 64) * 64);
      kr0 = ksrc[tid]; kr1 = ksrc[tid + 256];
      vr0 = *(const uint4*)(vt + (size_t)(bh * 64 + (tid >> 3)) * 2048 + (c + 1) * 64 + (tid & 7) * 8);
      int f2 = tid + 256;
      vr1 = *(const uint4*)(vt + (size_t)(bh * 64 + (f2 >> 3)) * 2048 + (c + 1) * 64 + (f2 & 7) * 8);
    }
    __syncthreads();  // staging visible

    const int lc = c - cbase;  // -4..3
#pragma unroll
    for (int qt = 0; qt < 4; qt++) {
      if (qt < lc || qt > lc + 4) continue;  // q-tile qt's window is c in [iq-4, iq]
      const int i0q = chunk * 256 + qt * 64;

      // S = Q K^T (scale+log2e pre-folded into q upstream)
      f32x4 sacc[4];
#pragma unroll
      for (int nb = 0; nb < 4; nb++) sacc[nb] = f32x4_zero();
#pragma unroll
      for (int kk = 0; kk < 2; kk++) {
#pragma unroll
        for (int nb = 0; nb < 4; nb++) {
          bf16x8 bfr = *(const bf16x8*)&ks[p][(nb * 16 + l16) * 64 + (((kk * 4 + qd) ^ (l16 & 7)) * 8)];
          sacc[nb] = __builtin_amdgcn_mfma_f32_16x16x32_bf16(qfr[qt][kk], bfr, sacc[nb], 0, 0, 0);
        }
      }

      // fixed-max softmax: p = exp2(s) (masked -> 0)
#pragma unroll
      for (int r = 0; r < 4; r++) {
        const int i = i0q + wid * 16 + qd * 4 + r;
        const int prow = qd * 4 + r;
#pragma unroll
        for (int nb = 0; nb < 4; nb++) {
          const int j = c * 64 + nb * 16 + l16;
          bool valid = (j <= i) && (j + 256 > i);
          float pv = valid ? exp2f(sacc[nb][r]) : 0.f;
          ps[wid][prow * 64 + (((nb * 2 + (l16 >> 3)) ^ (prow & 7)) * 8) + (l16 & 7)] = (bf16_t)pv;
        }
      }

      // ps is wave-private: wave-local fence (no s_barrier); rule #18 sched fence
      asm volatile("s_waitcnt lgkmcnt(0)" ::: "memory");
      __builtin_amdgcn_sched_barrier(0);

      // O += P V ; l += P * ones
      f32x4 lacc = f32x4_zero();
#pragma unroll
      for (int kk = 0; kk < 2; kk++) {
        bf16x8 afr = *(const bf16x8*)&ps[wid][l16 * 64 + (((kk * 4 + qd) ^ (l16 & 7)) * 8)];
        lacc = __builtin_amdgcn_mfma_f32_16x16x32_bf16(afr, bones, lacc, 0, 0, 0);
#pragma unroll
        for (int nb = 0; nb < 4; nb++) {
          bf16x8 bfr = *(const bf16x8*)&vts[p][(nb * 16 + l16) * 64 + (((kk * 4 + qd) ^ (l16 & 7)) * 8)];
          oacc[qt][nb] = __builtin_amdgcn_mfma_f32_16x16x32_bf16(afr, bfr, oacc[qt][nb], 0, 0, 0);
        }
      }
#pragma unroll
      for (int r = 0; r < 4; r++) l_i[qt][r] += lacc[r];
    }
  }

  // epilogue: ao[b][t][h*64+d] = O/l
#pragma unroll
  for (int qt = 0; qt < 4; qt++)
#pragma unroll
    for (int nb = 0; nb < 4; nb++)
#pragma unroll
      for (int r = 0; r < 4; r++) {
        int t = chunk * 256 + qt * 64 + wid * 16 + qd * 4 + r;
        ao[((size_t)(b * 2048 + t)) * 1024 + h * 64 + nb * 16 + l16] =
            (bf16_t)(oacc[qt][nb][r] / l_i[qt][r]);
      }
}

// ---------------------------------------------------------------- launch
extern "C" void kernel_launch(void* const* d_in, const int* in_sizes, int n_in,
                              void* d_out, int out_size, void* d_ws, size_t ws_size,
                              hipStream_t stream) {
  const float* x    = (const float*)d_in[0];  // [4,2048,1024]
  const float* cosp = (const float*)d_in[1];  // [1,2048,1,64]
  const float* sinp = (const float*)d_in[2];
  const float* qkvw = (const float*)d_in[3];  // [3072,1024]
  const float* outw = (const float*)d_in[4];  // [1024,1024]
  float* out = (float*)d_out;                 // [4,2048,1024]

  char* ws = (char*)d_ws;
  bf16_t* xb  = (bf16_t*)(ws + 0);
  bf16_t* qwb = (bf16_t*)(ws + 16777216);
  bf16_t* owb = (bf16_t*)(ws + 23068672);
  bf16_t* qhp = (bf16_t*)(ws + 25165824);   // [B,H,T,64] bf16 (RoPE'd q, scale folded)
  bf16_t* khp = (bf16_t*)(ws + 41943040);   // [B,H,T,64] bf16 (RoPE'd k)
  bf16_t* vtp = (bf16_t*)(ws + 58720256);   // [B*H,64,2048] bf16 (V TRANSPOSED)
  bf16_t* aop = (bf16_t*)(ws + 75497472);   // [B,T,1024] bf16

  cast3_kernel<<<12288, 256, 0, stream>>>(x, qkvw, outw, xb, qwb, owb);

  gemm_bt_kernel<1><<<dim3(32, 24), 512, 0, stream>>>(xb, qwb, nullptr, qhp, khp, vtp,
                                                      cosp, sinp, 8192, 3072, 1024);
  attn_kernel<<<dim3(64, 8), 256, 0, stream>>>(qhp, khp, vtp, aop);
  gemm_bt_kernel<0><<<dim3(32, 8), 512, 0, stream>>>(aop, owb, out, nullptr, nullptr, nullptr,
                                                     nullptr, nullptr, 8192, 1024, 1024);
}

// Round 12
// 212.386 us; speedup vs baseline: 1.0589x; 1.0589x over previous
//
#include <hip/hip_runtime.h>

typedef __bf16 bf16_t;
typedef __bf16 bf16x8 __attribute__((ext_vector_type(8)));
typedef __bf16 bf16x4 __attribute__((ext_vector_type(4)));
typedef float f32x4 __attribute__((ext_vector_type(4)));

#define GLOAD_LDS16(gptr, lptr)                                                              \
  __builtin_amdgcn_global_load_lds((const __attribute__((address_space(1))) void*)(gptr),    \
                                   (__attribute__((address_space(3))) void*)(lptr), 16, 0, 0)

__device__ __forceinline__ f32x4 f32x4_zero() {
  f32x4 v; v[0] = 0.f; v[1] = 0.f; v[2] = 0.f; v[3] = 0.f; return v;
}

// ---------------------------------------------------------------- fused casts f32 -> bf16
__global__ void cast3_kernel(const float* __restrict__ a, const float* __restrict__ b,
                             const float* __restrict__ c, bf16_t* __restrict__ oa,
                             bf16_t* __restrict__ ob, bf16_t* __restrict__ oc) {
  int i = blockIdx.x * blockDim.x + threadIdx.x;
  const float* src; bf16_t* dst; int j;
  if (i < 2097152) { src = a; dst = oa; j = i; }
  else if (i < 2883584) { src = b; dst = ob; j = i - 2097152; }
  else { src = c; dst = oc; j = i - 2883584; }
  float4 v = ((const float4*)src)[j];
  bf16x4 o;
  o[0] = (bf16_t)v.x; o[1] = (bf16_t)v.y; o[2] = (bf16_t)v.z; o[3] = (bf16_t)v.w;
  ((bf16x4*)dst)[j] = o;
}

// ---------------------------------------------------------------- GEMM  C[M,N] = A[M,K] * B[N,K]^T
// (byte-identical to rounds 8/9: 256x128 tile, BK=64, 8 waves, 3-slot ring, counted vmcnt(6),
//  XOR-granule swizzle, setprio; MODE-1 epilogue fuses RoPE for q/k and transposed V write)
#define GT_AELE 16384  // 256*64 bf16 (32KB)
#define GT_BELE 8192   // 128*64 bf16 (16KB)
#define GT_TILE (GT_AELE + GT_BELE)

__device__ __forceinline__ void gt_stage(const bf16_t* __restrict__ A,
                                         const bf16_t* __restrict__ B, bf16_t* buf,
                                         int bm, int bn, int t, int K, int tid) {
#pragma unroll
  for (int i = 0; i < 4; i++) {  // A: 256 rows x 8 granules of 16B
    int gi = tid + i * 512;
    int row = gi >> 3, g = gi & 7;
    const bf16_t* src = A + (size_t)(bm * 256 + row) * K + t * 64 + ((g ^ (row & 7)) << 3);
    GLOAD_LDS16(src, buf + gi * 8);
  }
#pragma unroll
  for (int i = 0; i < 2; i++) {  // B: 128 rows x 8 granules
    int gi = tid + i * 512;
    int row = gi >> 3, g = gi & 7;
    const bf16_t* src = B + (size_t)(bn * 128 + row) * K + t * 64 + ((g ^ (row & 7)) << 3);
    GLOAD_LDS16(src, buf + GT_AELE + gi * 8);
  }
}

template <int MODE>
__global__ __launch_bounds__(512, 1) void gemm_bt_kernel(
    const bf16_t* __restrict__ A, const bf16_t* __restrict__ B, float* __restrict__ C,
    bf16_t* __restrict__ oq, bf16_t* __restrict__ ok_, bf16_t* __restrict__ ov,
    const float* __restrict__ cosp, const float* __restrict__ sinp,
    int M, int N, int K) {
  __shared__ bf16_t lds[3 * GT_TILE];  // 147456 B

  const int tid = threadIdx.x;
  const int lane = tid & 63;
  const int wid = tid >> 6;
  const int wr = wid >> 1;      // 0..3  (M quadrant, 64 rows)
  const int wc = wid & 1;       // 0..1  (N half, 64 cols)
  const int l16 = lane & 15;
  const int qd = lane >> 4;
  const int bm = blockIdx.x, bn = blockIdx.y;

  f32x4 acc[4][4];
#pragma unroll
  for (int m = 0; m < 4; m++)
#pragma unroll
    for (int n = 0; n < 4; n++) acc[m][n] = f32x4_zero();

  const int NT = K >> 6;  // 16

  gt_stage(A, B, lds, bm, bn, 0, K, tid);
  gt_stage(A, B, lds + GT_TILE, bm, bn, 1, K, tid);
  asm volatile("s_waitcnt vmcnt(6)" ::: "memory");
  __builtin_amdgcn_s_barrier();
  __builtin_amdgcn_sched_barrier(0);

  int s = 0;  // buffer holding tile j
  for (int j = 0; j < NT; ++j) {
    if (j + 2 < NT) {
      int s2 = s + 2; if (s2 >= 3) s2 -= 3;
      gt_stage(A, B, lds + s2 * GT_TILE, bm, bn, j + 2, K, tid);
    }

    const bf16_t* bufc = lds + s * GT_TILE;
    bf16x8 af[4][2], bf[4][2];
#pragma unroll
    for (int m = 0; m < 4; m++)
#pragma unroll
      for (int kk = 0; kk < 2; kk++) {
        int row = wr * 64 + m * 16 + l16;
        af[m][kk] = *(const bf16x8*)&bufc[row * 64 + (((kk * 4 + qd) ^ (row & 7)) << 3)];
      }
#pragma unroll
    for (int n = 0; n < 4; n++)
#pragma unroll
      for (int kk = 0; kk < 2; kk++) {
        int row = wc * 64 + n * 16 + l16;
        bf[n][kk] = *(const bf16x8*)&bufc[GT_AELE + row * 64 + (((kk * 4 + qd) ^ (row & 7)) << 3)];
      }

    __builtin_amdgcn_s_setprio(1);
#pragma unroll
    for (int m = 0; m < 4; m++)
#pragma unroll
      for (int n = 0; n < 4; n++)
#pragma unroll
        for (int kk = 0; kk < 2; kk++)
          acc[m][n] = __builtin_amdgcn_mfma_f32_16x16x32_bf16(af[m][kk], bf[n][kk], acc[m][n], 0, 0, 0);
    __builtin_amdgcn_s_setprio(0);

    if (j + 2 < NT) {
      asm volatile("s_waitcnt vmcnt(6)" ::: "memory");
    } else {
      asm volatile("s_waitcnt vmcnt(0)" ::: "memory");
    }
    __builtin_amdgcn_s_barrier();
    __builtin_amdgcn_sched_barrier(0);
    s = (s == 2) ? 0 : s + 1;
  }

  if (MODE == 0) {
#pragma unroll
    for (int m = 0; m < 4; m++)
#pragma unroll
      for (int n = 0; n < 4; n++)
#pragma unroll
        for (int r = 0; r < 4; r++) {
          int row = bm * 256 + wr * 64 + m * 16 + qd * 4 + r;
          int col = bn * 128 + wc * 64 + n * 16 + l16;
          C[(size_t)row * N + col] = acc[m][n][r];
        }
  } else {
    const int colbase = bn * 128 + wc * 64;     // 64-aligned -> single head per wave
    const int part = colbase >> 10;             // uniform per block (bn 0-7 q, 8-15 k, 16-23 v)
    const int h = (colbase & 1023) >> 6;
    if (part == 2) {
      // v: transpose via per-wave 8KB LDS region (ring is dead after the K-loop).
      bf16_t* lw = lds + wid * 4096;  // [64 d][8 granules of 8 bf16]
#pragma unroll
      for (int m = 0; m < 4; m++)
#pragma unroll
        for (int n = 0; n < 4; n++) {
          int d = n * 16 + l16;
          int gr = (m * 2 + (qd >> 1)) ^ (d & 7);   // t-chunk (t_local>>3), swizzled
          bf16x4 w;
          w[0] = (bf16_t)acc[m][n][0];
          w[1] = (bf16_t)acc[m][n][1];
          w[2] = (bf16_t)acc[m][n][2];
          w[3] = (bf16_t)acc[m][n][3];
          *(bf16x4*)&lw[d * 64 + gr * 8 + (qd & 1) * 4] = w;
        }
      asm volatile("s_waitcnt lgkmcnt(0)" ::: "memory");
      __builtin_amdgcn_sched_barrier(0);
      const int rowbase = bm * 256 + wr * 64;      // 64-aligned -> single batch per wave
      const int bb = rowbase >> 11, tb = rowbase & 2047;
      bf16_t* vbase = ov + ((size_t)(bb * 16 + h) * 64) * 2048 + tb;
#pragma unroll
      for (int it = 0; it < 8; it++) {
        int d = it * 8 + (lane >> 3);
        int g = lane & 7;
        *(bf16x8*)&vbase[(size_t)d * 2048 + g * 8] =
            *(const bf16x8*)&lw[d * 64 + ((g ^ (d & 7)) << 3)];
      }
    } else {
      // q (part 0, 0.125*log2e folded) or k (part 1): fused RoPE in fp32.
      bf16_t* dst = (part == 0) ? oq : ok_;
      const float qsc = (part == 0) ? 0.18033688011112042f : 1.0f;
#pragma unroll
      for (int m = 0; m < 4; m++)
#pragma unroll
        for (int r = 0; r < 4; r++) {
          int row = bm * 256 + wr * 64 + m * 16 + qd * 4 + r;
          int b = row >> 11, t = row & 2047;
          size_t basei = (((size_t)(b * 16 + h)) * 2048 + t) * 64;
#pragma unroll
          for (int nb = 0; nb < 2; nb++) {
            int d = nb * 16 + l16;
            float xl = acc[m][nb][r];
            float xh = acc[m][nb + 2][r];
            float cl = cosp[t * 64 + d], ch = cosp[t * 64 + d + 32];
            float sl = sinp[t * 64 + d], sh = sinp[t * 64 + d + 32];
            dst[basei + d]      = (bf16_t)((xl * cl - xh * sl) * qsc);
            dst[basei + d + 32] = (bf16_t)((xh * ch + xl * sh) * qsc);
          }
        }
    }
  }
}

// ---------------------------------------------------------------- banded flash attention
// Multi-q-tile blocks (4 q-tiles / 256 rows, union-window sweep). NEW this round:
// ALL staging via global_load_lds with pre-swizzled per-lane SOURCE (m173 pattern;
// swz4 is an involution; LDS dst is lane-linear = required wave-uniform+lane*16 form).
// Software pipeline: issue c+1's 8 DMA loads right after the barrier, compute tile c,
// then vmcnt(0) (loads had the whole compute phase to land) + ONE raw s_barrier/iter.
// No staging registers (VGPR ~140), no __syncthreads vmcnt-drain before compute
// (r9/r11's hidden serialization). Q staged once via the same DMA path (prologue drain).
// Fragment math identical to r9: V transposed upstream -> PV == QK^T structurally;
// wave-private ps -> lgkmcnt fence; fixed-max softmax; ones-MFMA row-sum.
__global__ __launch_bounds__(256) void attn_kernel(
    const bf16_t* __restrict__ qh, const bf16_t* __restrict__ kh,
    const bf16_t* __restrict__ vt, bf16_t* __restrict__ ao) {
  __shared__ bf16_t qs[4][64 * 64];   // 32KB
  __shared__ bf16_t ks[2][64 * 64];   // 16KB double buffer
  __shared__ bf16_t vts[2][64 * 64];  // 16KB double buffer
  __shared__ bf16_t ps[4][16 * 64];   // 8KB per-wave P   -> 72KB total

  const int tid = threadIdx.x;
  const int lane = tid & 63;
  const int wid = tid >> 6;
  const int l16 = lane & 15;
  const int qd = lane >> 4;

  const int bh = blockIdx.x;          // 0..63
  const int chunk = blockIdx.y;       // 0..7 (256 q-rows each)
  const int b = bh >> 4, h = bh & 15;

  // DMA staging geometry: granule f = row*8 + g (16B each); source column pre-swizzled
  const int f0 = tid, f1 = tid + 256;
  const int r0 = f0 >> 3, g0 = f0 & 7;
  const int r1 = f1 >> 3, g1 = f1 & 7;
  const int sg0 = (g0 ^ (r0 & 7)) << 3;   // swizzled elem offset within 64-elem row
  const int sg1 = (g1 ^ (r1 & 7)) << 3;

  {  // stage all 4 Q tiles (swz4 content) via DMA
    const bf16_t* qsrc = qh + ((size_t)bh * 2048 + chunk * 256) * 64;
#pragma unroll
    for (int qt = 0; qt < 4; qt++) {
      GLOAD_LDS16(qsrc + (size_t)(qt * 64 + r0) * 64 + sg0, &qs[qt][f0 * 8]);
      GLOAD_LDS16(qsrc + (size_t)(qt * 64 + r1) * 64 + sg1, &qs[qt][f1 * 8]);
    }
  }

  const int cbase = chunk * 4;
  const int c0 = (cbase >= 4) ? cbase - 4 : 0;
  const int c1 = cbase + 3;

  const bf16_t* kbase = kh + (size_t)bh * 2048 * 64;   // rows t, 64-elem stride
  const bf16_t* vbase = vt + (size_t)bh * 64 * 2048;   // rows d, 2048-elem stride

  // stage K[c] and VT[c] into buffer p (8 DMA loads)
  auto stage_kv = [&](int c, int p) {
    GLOAD_LDS16(kbase + (size_t)(c * 64 + r0) * 64 + sg0, &ks[p][f0 * 8]);
    GLOAD_LDS16(kbase + (size_t)(c * 64 + r1) * 64 + sg1, &ks[p][f1 * 8]);
    GLOAD_LDS16(vbase + (size_t)r0 * 2048 + c * 64 + sg0, &vts[p][f0 * 8]);
    GLOAD_LDS16(vbase + (size_t)r1 * 2048 + c * 64 + sg1, &vts[p][f1 * 8]);
  };

  stage_kv(c0, c0 & 1);
  asm volatile("s_waitcnt vmcnt(0)" ::: "memory");  // Q + first K/VT landed
  __builtin_amdgcn_s_barrier();
  __builtin_amdgcn_sched_barrier(0);

  bf16x8 bones;
#pragma unroll
  for (int e = 0; e < 8; e++) bones[e] = (bf16_t)1.0f;

  f32x4 oacc[4][4];          // [qt][nb]
  float l_i[4][4];           // [qt][r]
#pragma unroll
  for (int qt = 0; qt < 4; qt++)
#pragma unroll
    for (int nb = 0; nb < 4; nb++) {
      oacc[qt][nb] = f32x4_zero();
      l_i[qt][nb] = 0.f;
    }

  for (int c = c0; c <= c1; c++) {
    const int p = c & 1;
    if (c < c1) stage_kv(c + 1, p ^ 1);  // async DMA; overlaps compute below

    const int lc = c - cbase;  // -4..3
#pragma unroll
    for (int qt = 0; qt < 4; qt++) {
      if (qt < lc || qt > lc + 4) continue;  // q-tile qt's window is c in [iq-4, iq]
      const int i0q = chunk * 256 + qt * 64;

      // S = Q K^T (scale+log2e pre-folded into q upstream)
      f32x4 sacc[4];
#pragma unroll
      for (int nb = 0; nb < 4; nb++) sacc[nb] = f32x4_zero();
#pragma unroll
      for (int kk = 0; kk < 2; kk++) {
        bf16x8 afr = *(const bf16x8*)&qs[qt][(wid * 16 + l16) * 64 + (((kk * 4 + qd) ^ (l16 & 7)) * 8)];
#pragma unroll
        for (int nb = 0; nb < 4; nb++) {
          bf16x8 bfr = *(const bf16x8*)&ks[p][(nb * 16 + l16) * 64 + (((kk * 4 + qd) ^ (l16 & 7)) * 8)];
          sacc[nb] = __builtin_amdgcn_mfma_f32_16x16x32_bf16(afr, bfr, sacc[nb], 0, 0, 0);
        }
      }

      // fixed-max softmax: p = exp2(s) (masked -> 0)
#pragma unroll
      for (int r = 0; r < 4; r++) {
        const int i = i0q + wid * 16 + qd * 4 + r;
        const int prow = qd * 4 + r;
#pragma unroll
        for (int nb = 0; nb < 4; nb++) {
          const int j = c * 64 + nb * 16 + l16;
          bool valid = (j <= i) && (j + 256 > i);
          float pv = valid ? exp2f(sacc[nb][r]) : 0.f;
          ps[wid][prow * 64 + (((nb * 2 + (l16 >> 3)) ^ (prow & 7)) * 8) + (l16 & 7)] = (bf16_t)pv;
        }
      }

      // ps is wave-private: wave-local fence (no s_barrier); rule #18 sched fence
      asm volatile("s_waitcnt lgkmcnt(0)" ::: "memory");
      __builtin_amdgcn_sched_barrier(0);

      // O += P V ; l += P * ones
      f32x4 lacc = f32x4_zero();
#pragma unroll
      for (int kk = 0; kk < 2; kk++) {
        bf16x8 afr = *(const bf16x8*)&ps[wid][l16 * 64 + (((kk * 4 + qd) ^ (l16 & 7)) * 8)];
        lacc = __builtin_amdgcn_mfma_f32_16x16x32_bf16(afr, bones, lacc, 0, 0, 0);
#pragma unroll
        for (int nb = 0; nb < 4; nb++) {
          bf16x8 bfr = *(const bf16x8*)&vts[p][(nb * 16 + l16) * 64 + (((kk * 4 + qd) ^ (l16 & 7)) * 8)];
          oacc[qt][nb] = __builtin_amdgcn_mfma_f32_16x16x32_bf16(afr, bfr, oacc[qt][nb], 0, 0, 0);
        }
      }
#pragma unroll
      for (int r = 0; r < 4; r++) l_i[qt][r] += lacc[r];
    }

    // end of iteration: next tile's DMA (issued at top) has had the whole compute
    // phase to land -> this wait is cheap. ONE raw barrier per iteration.
    if (c < c1) {
      asm volatile("s_waitcnt vmcnt(0)" ::: "memory");
      __builtin_amdgcn_s_barrier();
      __builtin_amdgcn_sched_barrier(0);
    }
  }

  // epilogue: ao[b][t][h*64+d] = O/l
#pragma unroll
  for (int qt = 0; qt < 4; qt++)
#pragma unroll
    for (int nb = 0; nb < 4; nb++)
#pragma unroll
      for (int r = 0; r < 4; r++) {
        int t = chunk * 256 + qt * 64 + wid * 16 + qd * 4 + r;
        ao[((size_t)(b * 2048 + t)) * 1024 + h * 64 + nb * 16 + l16] =
            (bf16_t)(oacc[qt][nb][r] / l_i[qt][r]);
      }
}

// ---------------------------------------------------------------- launch
extern "C" void kernel_launch(void* const* d_in, const int* in_sizes, int n_in,
                              void* d_out, int out_size, void* d_ws, size_t ws_size,
                              hipStream_t stream) {
  const float* x    = (const float*)d_in[0];  // [4,2048,1024]
  const float* cosp = (const float*)d_in[1];  // [1,2048,1,64]
  const float* sinp = (const float*)d_in[2];
  const float* qkvw = (const float*)d_in[3];  // [3072,1024]
  const float* outw = (const float*)d_in[4];  // [1024,1024]
  float* out = (float*)d_out;                 // [4,2048,1024]

  char* ws = (char*)d_ws;
  bf16_t* xb  = (bf16_t*)(ws + 0);
  bf16_t* qwb = (bf16_t*)(ws + 16777216);
  bf16_t* owb = (bf16_t*)(ws + 23068672);
  bf16_t* qhp = (bf16_t*)(ws + 25165824);   // [B,H,T,64] bf16 (RoPE'd q, scale folded)
  bf16_t* khp = (bf16_t*)(ws + 41943040);   // [B,H,T,64] bf16 (RoPE'd k)
  bf16_t* vtp = (bf16_t*)(ws + 58720256);   // [B*H,64,2048] bf16 (V TRANSPOSED)
  bf16_t* aop = (bf16_t*)(ws + 75497472);   // [B,T,1024] bf16

  cast3_kernel<<<12288, 256, 0, stream>>>(x, qkvw, outw, xb, qwb, owb);

  gemm_bt_kernel<1><<<dim3(32, 24), 512, 0, stream>>>(xb, qwb, nullptr, qhp, khp, vtp,
                                                      cosp, sinp, 8192, 3072, 1024);
  attn_kernel<<<dim3(64, 8), 256, 0, stream>>>(qhp, khp, vtp, aop);
  gemm_bt_kernel<0><<<dim3(32, 8), 512, 0, stream>>>(aop, owb, out, nullptr, nullptr, nullptr,
                                                     nullptr, nullptr, 8192, 1024, 1024);
}